// Round 6
// baseline (59.553 us; speedup 1.0000x reference)
//
#include <hip/hip_runtime.h>
#include <hip/hip_bf16.h>
#include <math.h>

#define LA 1536
#define LS 512
#define LT 2048
#define CC 256
#define NH 4
#define DKH 64
#define NB 4
#define NT (LT / 64)
#define NTA (LA / 64)     // 24 audio tiles
#define SZ ((size_t)NB * LT * CC)

// (1/sqrt(64)) * log2(e): softmax runs in exp2 domain, folded into Q
#define QSCALE 0.1803368801111244f

typedef _Float16 f16;
typedef __attribute__((ext_vector_type(8))) _Float16 f16x8;
typedef __attribute__((ext_vector_type(4))) _Float16 f16x4;
typedef __attribute__((ext_vector_type(4))) float f32x4;

__device__ inline f16x8 cvt8(const float4 a, const float4 b) {
    f16x8 h;
    h[0] = (_Float16)a.x; h[1] = (_Float16)a.y; h[2] = (_Float16)a.z; h[3] = (_Float16)a.w;
    h[4] = (_Float16)b.x; h[5] = (_Float16)b.y; h[6] = (_Float16)b.z; h[7] = (_Float16)b.w;
    return h;
}

// ---------------------------------------------------------------------------
// Kernel 1: fused QKV projection, fp16 MFMA, 128x64 tiles.
// Q gets QSCALE folded in. V transposed Vt[(b*NH+h)*DKH+d][l] via LDS.
// ---------------------------------------------------------------------------
__global__ __launch_bounds__(256) void qkv_mfma(
    const float* __restrict__ audio, const float* __restrict__ text,
    const float* __restrict__ Wq, const float* __restrict__ bq,
    const float* __restrict__ Wk, const float* __restrict__ bk,
    const float* __restrict__ Wv, const float* __restrict__ bv,
    f16* __restrict__ Qh, f16* __restrict__ Kh, f16* __restrict__ Vth)
{
    __shared__ f16 smem[128 * 64 + 64 * 64];
    f16* As = smem;
    f16* Bs = smem + 128 * 64;

    const int tid = threadIdx.x;
    const int w = tid >> 6, l = tid & 63;
    const int g = l >> 4, r = l & 15;

    const int m0 = blockIdx.x * 128;
    const int n0 = blockIdx.y * 64;
    const int mat = n0 >> 8;          // 0=Q 1=K 2=V
    const int ch0 = n0 & 255;

    const float* W    = (mat == 0) ? Wq : (mat == 1) ? Wk : Wv;
    const float* bias = (mat == 0) ? bq : (mat == 1) ? bk : bv;

    const int b  = m0 >> 11;
    const int l0 = m0 & 2047;

    f32x4 acc[2][4] = {};

    for (int k0 = 0; k0 < CC; k0 += 64) {
        #pragma unroll
        for (int m = 0; m < 4; ++m) {
            const int idx = m * 256 + tid;
            const int row = idx >> 3, c = idx & 7;
            const int lrow = l0 + row;
            const float* src = (lrow < LA)
                ? (audio + ((size_t)b * LA + lrow) * CC + k0 + c * 8)
                : (text  + ((size_t)b * LS + (lrow - LA)) * CC + k0 + c * 8);
            const float4 x0 = *(const float4*)src;
            const float4 x1 = *(const float4*)(src + 4);
            *(f16x8*)(As + row * 64 + ((c ^ (row & 7)) << 3)) = cvt8(x0, x1);
        }
        #pragma unroll
        for (int m = 0; m < 2; ++m) {
            const int idx = m * 256 + tid;
            const int row = idx >> 3, c = idx & 7;
            const float* src = W + (size_t)(ch0 + row) * CC + k0 + c * 8;
            const float4 x0 = *(const float4*)src;
            const float4 x1 = *(const float4*)(src + 4);
            *(f16x8*)(Bs + row * 64 + ((c ^ (row & 7)) << 3)) = cvt8(x0, x1);
        }
        __syncthreads();
        #pragma unroll
        for (int kc = 0; kc < 2; ++kc) {
            f16x8 af[2];
            #pragma unroll
            for (int i = 0; i < 2; ++i) {
                const int row = w * 32 + i * 16 + r;
                const int c = kc * 4 + g;
                af[i] = *(const f16x8*)(As + row * 64 + ((c ^ (row & 7)) << 3));
            }
            f16x8 bf[4];
            #pragma unroll
            for (int j = 0; j < 4; ++j) {
                const int row = j * 16 + r;
                const int c = kc * 4 + g;
                bf[j] = *(const f16x8*)(Bs + row * 64 + ((c ^ (row & 7)) << 3));
            }
            #pragma unroll
            for (int i = 0; i < 2; ++i)
                #pragma unroll
                for (int j = 0; j < 4; ++j)
                    acc[i][j] = __builtin_amdgcn_mfma_f32_16x16x32_f16(af[i], bf[j], acc[i][j], 0, 0, 0);
        }
        __syncthreads();
    }

    float bcol[4];
    #pragma unroll
    for (int j = 0; j < 4; ++j) bcol[j] = bias[ch0 + j * 16 + r];

    if (mat <= 1) {
        f16* Out = (mat == 0) ? Qh : Kh;
        const float osc = (mat == 0) ? QSCALE : 1.0f;
        #pragma unroll
        for (int i = 0; i < 2; ++i)
            #pragma unroll
            for (int e = 0; e < 4; ++e) {
                const int m = m0 + w * 32 + i * 16 + g * 4 + e;
                #pragma unroll
                for (int j = 0; j < 4; ++j)
                    Out[(size_t)m * CC + ch0 + j * 16 + r] =
                        (_Float16)((acc[i][j][e] + bcol[j]) * osc);
            }
    } else {
        // V: stage C^T in LDS (Ts[64 n][136 m-pad]), then coalesced vec8 store.
        f16* Ts = smem;
        #pragma unroll
        for (int i = 0; i < 2; ++i)
            #pragma unroll
            for (int e = 0; e < 4; ++e) {
                const int ml = w * 32 + i * 16 + g * 4 + e;
                #pragma unroll
                for (int j = 0; j < 4; ++j)
                    Ts[(j * 16 + r) * 136 + ml] = (_Float16)(acc[i][j][e] + bcol[j]);
            }
        __syncthreads();
        const int b2 = m0 >> 11, l0m = m0 & 2047;
        #pragma unroll
        for (int u = 0; u < 4; ++u) {
            const int idx = u * 256 + tid;
            const int nl = idx >> 4, mc = idx & 15;
            const f16x8 vv = *(const f16x8*)(Ts + nl * 136 + mc * 8);
            const int nglob = ch0 + nl;
            const int hh = nglob >> 6, dd = nglob & 63;
            *(f16x8*)(Vth + ((size_t)((b2 * NH + hh) * DKH + dd)) * LT + l0m + mc * 8) = vv;
        }
    }
}

// ---------------------------------------------------------------------------
// Kernel 2: flash attention, fp16 MFMA, inverted mask.
// 4 waves = 2 tile-split groups x 2 waves; EACH WAVE OWNS 32 q-ROWS (2 frags)
// so each K/V LDS tile read serves 2x the work of round 4 (LDS-BW was the
// bottleneck). Single K/V buffer per group + reg-staged next tile; 2 barriers
// per iteration. exp2-domain softmax (QSCALE pre-folded), exact defer-rescale.
// Group-1 partials merged through an LDS union over Ps.
// ---------------------------------------------------------------------------
__global__ __launch_bounds__(256) void attn_f16(
    const f16* __restrict__ Q, const f16* __restrict__ K,
    const f16* __restrict__ Vt,
    const int* __restrict__ slen, const int* __restrict__ tlen,
    f16* __restrict__ AO)
{
    __shared__ f16 Ks[2][4096];                 // [group][key*64+d'], swizzled
    __shared__ f16 Vts[2][4096];                // [group][d*64+key'], swizzled
    __shared__ __align__(16) f16 Ps[4][2304];   // per-wave P (32 rows x 72);
                                                // union: Oc f32[4096] | ML1 f32[128]

    const int tid = threadIdx.x;
    const int w = tid >> 6, l = tid & 63;
    const int gid = w >> 1, wg = w & 1;
    const int g = l >> 4, r = l & 15;

    const int q0 = blockIdx.x * 64;
    const int h  = blockIdx.y;
    const int b  = blockIdx.z;

    const int ilen = slen[b];
    const int kcap = LA + tlen[b];
    const int nskip = ilen >> 6;
    int ntskip = 0;
    if (q0 >= LA) {
        const int skipmax = min(q0 - 63, kcap - 64);
        const int d = skipmax - LA;
        ntskip = (d < 0) ? 0 : ((d >> 6) + 1);
    }
    const int nAudio = NTA - nskip;                  // >= 1
    const int nProc  = nAudio + (NT - NTA) - ntskip; // >= 2
    const int nIter  = (nProc + 1) >> 1;

    const int qbase = q0 + 32 * wg;

    // Q fragments for both q-frags (QSCALE pre-folded by qkv_mfma)
    f16x8 qf[2][2];   // [j][ch]
    #pragma unroll
    for (int j = 0; j < 2; ++j)
        #pragma unroll
        for (int ch = 0; ch < 2; ++ch)
            qf[j][ch] = *(const f16x8*)(Q + ((size_t)(b * LT) + qbase + 16 * j + r) * CC
                                        + h * DKH + ch * 32 + g * 8);

    // staging: 128 threads per group, 4 vec8 rows each for K and V
    const int tg = tid & 127;
    const int rowb = tg >> 3, scc = tg & 7;
    const int c2 = ((scc ^ (rowb & 7)) << 3);
    const int sbase = rowb * 64 + c2;           // + u*1024

    #define TILE_OF(p) ((p) < nAudio ? (nskip + (p)) : (NTA + ntskip + ((p) - nAudio)))

    {   // prologue: stage this group's first tile
        const int k0 = TILE_OF(gid) * 64;
        #pragma unroll
        for (int u = 0; u < 4; ++u) {
            const int row = u * 16 + rowb;
            *(f16x8*)(Ks[gid] + u * 1024 + sbase) =
                *(const f16x8*)(K + ((size_t)(b * LT) + k0 + row) * CC + h * DKH + scc * 8);
            *(f16x8*)(Vts[gid] + u * 1024 + sbase) =
                *(const f16x8*)(Vt + ((size_t)((b * NH + h) * DKH) + row) * LT + k0 + scc * 8);
        }
    }

    float m_run[2] = {-1e30f, -1e30f}, l_run[2] = {0.0f, 0.0f};
    f32x4 o[4][2] = {};   // o[dsb][j][e]: O[q = 32wg+16j+4g+e][d = 16dsb+r]

    for (int i = 0; i < nIter; ++i) {
        __syncthreads();                       // A: staged tiles visible
        const int pcur = 2 * i + gid;
        const bool curV = pcur < nProc;
        const bool nxtV = (pcur + 2) < nProc;

        f16x8 kr[4], vr[4];
        if (nxtV) {
            const int kn = TILE_OF(pcur + 2) * 64;
            #pragma unroll
            for (int u = 0; u < 4; ++u) {
                const int row = u * 16 + rowb;
                kr[u] = *(const f16x8*)(K + ((size_t)(b * LT) + kn + row) * CC + h * DKH + scc * 8);
                vr[u] = *(const f16x8*)(Vt + ((size_t)((b * NH + h) * DKH) + row) * LT + kn + scc * 8);
            }
        }

        if (curV) {
            const int kt = TILE_OF(pcur);
            const int k0 = kt * 64;

            // ---- S^T = K . Q^T for both q-frags (A-frag read shared)
            f32x4 sacc[4][2] = {};
            #pragma unroll
            for (int s = 0; s < 4; ++s) {
                const int arow = 16 * s + r;
                #pragma unroll
                for (int ch = 0; ch < 2; ++ch) {
                    const f16x8 a = *(const f16x8*)(Ks[gid] + arow * 64 + ((((ch * 4 + g) ^ (arow & 7)) & 7) << 3));
                    #pragma unroll
                    for (int j = 0; j < 2; ++j)
                        sacc[s][j] = __builtin_amdgcn_mfma_f32_16x16x32_f16(a, qf[j][ch], sacc[s][j], 0, 0, 0);
                }
            }

            const int mode = (kt < NTA) ? ((k0 >= ilen) ? 0 : 1)
                                        : ((q0 < LA) ? 0 : 2);

            // ---- per-frag mask + online softmax + P store
            #pragma unroll
            for (int j = 0; j < 2; ++j) {
                const int qrow = qbase + 16 * j + r;
                float sv[16];
                if (mode == 0) {
                    #pragma unroll
                    for (int s = 0; s < 4; ++s)
                        #pragma unroll
                        for (int e = 0; e < 4; ++e) sv[s * 4 + e] = sacc[s][j][e];
                } else if (mode == 1) {
                    #pragma unroll
                    for (int s = 0; s < 4; ++s)
                        #pragma unroll
                        for (int e = 0; e < 4; ++e) {
                            const int kk = k0 + 16 * s + 4 * g + e;
                            sv[s * 4 + e] = (kk >= ilen) ? sacc[s][j][e] : -INFINITY;
                        }
                } else {
                    #pragma unroll
                    for (int s = 0; s < 4; ++s)
                        #pragma unroll
                        for (int e = 0; e < 4; ++e) {
                            const int kk = k0 + 16 * s + 4 * g + e;
                            sv[s * 4 + e] = (kk > qrow || kk >= kcap) ? sacc[s][j][e] : -INFINITY;
                        }
                }

                float mloc = -1e30f;
                #pragma unroll
                for (int u = 0; u < 16; ++u) mloc = fmaxf(mloc, sv[u]);
                mloc = fmaxf(mloc, __shfl_xor(mloc, 16));
                mloc = fmaxf(mloc, __shfl_xor(mloc, 32));
                const float m_new = fmaxf(m_run[j], mloc);

                float ssum = 0.0f;
                f16x4 ph[4];
                #pragma unroll
                for (int s = 0; s < 4; ++s)
                    #pragma unroll
                    for (int e = 0; e < 4; ++e) {
                        const float p = exp2f(sv[s * 4 + e] - m_new);   // exp2(-inf)=0
                        ph[s][e] = (_Float16)p;
                        ssum += p;
                    }
                ssum += __shfl_xor(ssum, 16);
                ssum += __shfl_xor(ssum, 32);

                if (__all(m_new == m_run[j])) {        // exact defer (sc==1)
                    l_run[j] += ssum;
                } else {
                    const float sc = exp2f(m_run[j] - m_new);
                    l_run[j] = l_run[j] * sc + ssum;
                    m_run[j] = m_new;
                    #pragma unroll
                    for (int e = 0; e < 4; ++e) {
                        const float scr = __shfl(sc, 4 * g + e);
                        #pragma unroll
                        for (int dsb = 0; dsb < 4; ++dsb) o[dsb][j][e] *= scr;
                    }
                }

                #pragma unroll
                for (int s = 0; s < 4; ++s)
                    *(f16x4*)(&Ps[w][0] + (16 * j + r) * 72 + 16 * s + 4 * g) = ph[s];
            }

            // ---- O += P . V  (B-frag read shared across q-frags)
            #pragma unroll
            for (int ch = 0; ch < 2; ++ch) {
                f16x8 a[2];
                #pragma unroll
                for (int j = 0; j < 2; ++j)
                    a[j] = *(const f16x8*)(&Ps[w][0] + (16 * j + r) * 72 + ch * 32 + g * 8);
                #pragma unroll
                for (int dsb = 0; dsb < 4; ++dsb) {
                    const int vrow = 16 * dsb + r;
                    const f16x8 bf = *(const f16x8*)(Vts[gid] + vrow * 64 + ((((ch * 4 + g) ^ (vrow & 7)) & 7) << 3));
                    #pragma unroll
                    for (int j = 0; j < 2; ++j)
                        o[dsb][j] = __builtin_amdgcn_mfma_f32_16x16x32_f16(a[j], bf, o[dsb][j], 0, 0, 0);
                }
            }
        }

        __syncthreads();                       // B: LDS reads done
        if (nxtV) {
            #pragma unroll
            for (int u = 0; u < 4; ++u) {
                *(f16x8*)(Ks[gid] + u * 1024 + sbase) = kr[u];
                *(f16x8*)(Vts[gid] + u * 1024 + sbase) = vr[u];
            }
        }
    }

    // ---- merge group partials (Oc/ML1 union over Ps; last barrier B protects)
    float* OcF = (float*)&Ps[0][0];     // [ (wg*2+j)*4+dsb ][ lane*4+e ] : 16 KB
    float* ML1 = OcF + 4096;            // [qloc][2] : 512 B
    if (gid == 1) {
        #pragma unroll
        for (int j = 0; j < 2; ++j) {
            #pragma unroll
            for (int dsb = 0; dsb < 4; ++dsb)
                *(f32x4*)(OcF + (((wg * 2 + j) * 4 + dsb) << 8) + (l << 2)) = o[dsb][j];
            if (g == 0) {
                ML1[(32 * wg + 16 * j + r) * 2 + 0] = m_run[j];
                ML1[(32 * wg + 16 * j + r) * 2 + 1] = l_run[j];
            }
        }
    }
    __syncthreads();

    if (gid == 0) {
        #pragma unroll
        for (int j = 0; j < 2; ++j) {
            #pragma unroll
            for (int e = 0; e < 4; ++e) {
                const int qloc = 32 * wg + 16 * j + 4 * g + e;
                const float m0v = __shfl(m_run[j], 4 * g + e);
                const float l0v = __shfl(l_run[j], 4 * g + e);
                const float m1v = ML1[qloc * 2 + 0];
                const float l1v = ML1[qloc * 2 + 1];
                const float mt = fmaxf(m0v, m1v);
                const float c0 = exp2f(m0v - mt);
                const float c1 = exp2f(m1v - mt);
                const float inv = 1.0f / (l0v * c0 + l1v * c1);
                #pragma unroll
                for (int dsb = 0; dsb < 4; ++dsb) {
                    const float v = (o[dsb][j][e] * c0
                                   + OcF[(((wg * 2 + j) * 4 + dsb) << 8) + (l << 2) + e] * c1) * inv;
                    AO[((size_t)(b * LT) + q0 + qloc) * CC + h * DKH + 16 * dsb + r] = (_Float16)v;
                }
            }
        }
    }
    #undef TILE_OF
}

// ---------------------------------------------------------------------------
// Kernel 3: output projection, fp16 MFMA (X already f16), fp32 out.
// ---------------------------------------------------------------------------
__global__ __launch_bounds__(256) void out_mfma(
    const f16* __restrict__ X, const float* __restrict__ Wo,
    const float* __restrict__ bo, float* __restrict__ Out)
{
    __shared__ f16 As[128 * 64];
    __shared__ f16 Bs[64 * 64];

    const int tid = threadIdx.x;
    const int w = tid >> 6, l = tid & 63;
    const int g = l >> 4, r = l & 15;

    const int m0 = blockIdx.x * 128;
    const int n0 = blockIdx.y * 64;

    f32x4 acc[2][4] = {};

    for (int k0 = 0; k0 < CC; k0 += 64) {
        #pragma unroll
        for (int m = 0; m < 4; ++m) {
            const int idx = m * 256 + tid;
            const int row = idx >> 3, c = idx & 7;
            *(f16x8*)(As + row * 64 + ((c ^ (row & 7)) << 3)) =
                *(const f16x8*)(X + (size_t)(m0 + row) * CC + k0 + c * 8);
        }
        #pragma unroll
        for (int m = 0; m < 2; ++m) {
            const int idx = m * 256 + tid;
            const int row = idx >> 3, c = idx & 7;
            const float* src = Wo + (size_t)(n0 + row) * CC + k0 + c * 8;
            const float4 x0 = *(const float4*)src;
            const float4 x1 = *(const float4*)(src + 4);
            *(f16x8*)(Bs + row * 64 + ((c ^ (row & 7)) << 3)) = cvt8(x0, x1);
        }
        __syncthreads();
        #pragma unroll
        for (int kc = 0; kc < 2; ++kc) {
            f16x8 af[2];
            #pragma unroll
            for (int i = 0; i < 2; ++i) {
                const int row = w * 32 + i * 16 + r;
                const int c = kc * 4 + g;
                af[i] = *(const f16x8*)(As + row * 64 + ((c ^ (row & 7)) << 3));
            }
            f16x8 bf[4];
            #pragma unroll
            for (int j = 0; j < 4; ++j) {
                const int row = j * 16 + r;
                const int c = kc * 4 + g;
                bf[j] = *(const f16x8*)(Bs + row * 64 + ((c ^ (row & 7)) << 3));
            }
            #pragma unroll
            for (int i = 0; i < 2; ++i)
                #pragma unroll
                for (int j = 0; j < 4; ++j)
                    acc[i][j] = __builtin_amdgcn_mfma_f32_16x16x32_f16(af[i], bf[j], acc[i][j], 0, 0, 0);
        }
        __syncthreads();
    }

    float bcol[4];
    #pragma unroll
    for (int j = 0; j < 4; ++j) bcol[j] = bo[n0 + j * 16 + r];

    #pragma unroll
    for (int i = 0; i < 2; ++i)
        #pragma unroll
        for (int e = 0; e < 4; ++e) {
            const int m = m0 + w * 32 + i * 16 + g * 4 + e;
            #pragma unroll
            for (int j = 0; j < 4; ++j)
                Out[(size_t)m * CC + n0 + j * 16 + r] = acc[i][j][e] + bcol[j];
        }
}

// ---------------------------------------------------------------------------
extern "C" void kernel_launch(void* const* d_in, const int* in_sizes, int n_in,
                              void* d_out, int out_size, void* d_ws, size_t ws_size,
                              hipStream_t stream)
{
    const float* audio = (const float*)d_in[0];
    const float* text  = (const float*)d_in[1];
    const int*   slen  = (const int*)d_in[2];
    const int*   tlen  = (const int*)d_in[3];
    const float* Wq = (const float*)d_in[4];
    const float* bq = (const float*)d_in[5];
    const float* Wk = (const float*)d_in[6];
    const float* bk = (const float*)d_in[7];
    const float* Wv = (const float*)d_in[8];
    const float* bv = (const float*)d_in[9];
    const float* Wo = (const float*)d_in[10];
    const float* bo = (const float*)d_in[11];
    float* out = (float*)d_out;

    f16* Qh  = (f16*)d_ws;
    f16* Kh  = Qh + SZ;
    f16* Vth = Kh + SZ;
    f16* AOh = Vth + SZ;

    qkv_mfma<<<dim3(64, 12), 256, 0, stream>>>(audio, text, Wq, bq, Wk, bk, Wv, bv,
                                               Qh, Kh, Vth);
    attn_f16<<<dim3(LT / 64, NH, NB), 256, 0, stream>>>(Qh, Kh, Vth, slen, tlen, AOh);
    out_mfma<<<dim3(64, 4), 256, 0, stream>>>(AOh, Wo, bo, out);
}

// Round 7
// 51.134 us; speedup vs baseline: 1.1647x; 1.1647x over previous
//
#include <hip/hip_runtime.h>
#include <hip/hip_bf16.h>
#include <math.h>

#define LA 1536
#define LS 512
#define LT 2048
#define CC 256
#define NH 4
#define DKH 64
#define NB 4
#define NT (LT / 64)
#define NTA (LA / 64)     // 24 audio tiles
#define SZ ((size_t)NB * LT * CC)

// (1/sqrt(64)) * log2(e): softmax runs in exp2 domain, folded into Q
#define QSCALE 0.1803368801111244f

typedef _Float16 f16;
typedef __attribute__((ext_vector_type(8))) _Float16 f16x8;
typedef __attribute__((ext_vector_type(4))) _Float16 f16x4;
typedef __attribute__((ext_vector_type(4))) float f32x4;

__device__ inline f16x8 cvt8(const float4 a, const float4 b) {
    f16x8 h;
    h[0] = (_Float16)a.x; h[1] = (_Float16)a.y; h[2] = (_Float16)a.z; h[3] = (_Float16)a.w;
    h[4] = (_Float16)b.x; h[5] = (_Float16)b.y; h[6] = (_Float16)b.z; h[7] = (_Float16)b.w;
    return h;
}

// K-row permutation: pi(32a + 8g + 4t + e) = 32a + 16t + 4g + e.
// With K stored at row pi(key), the swapped-QK^T output lands so that lane
// (g,r) holds keys {32ch + 8g + 0..7} -> PV A-frag = own registers, no LDS.
#define PROW(j) (((j) & 32) | ((((j) >> 2) & 1) << 4) | ((((j) >> 3) & 3) << 2) | ((j) & 3))

// ---------------------------------------------------------------------------
// Kernel 1: fused QKV projection, fp16 MFMA, 128x64 tiles.
// Q gets QSCALE folded in. V transposed Vt[(b*NH+h)*DKH+d][l] via LDS.
// ---------------------------------------------------------------------------
__global__ __launch_bounds__(256) void qkv_mfma(
    const float* __restrict__ audio, const float* __restrict__ text,
    const float* __restrict__ Wq, const float* __restrict__ bq,
    const float* __restrict__ Wk, const float* __restrict__ bk,
    const float* __restrict__ Wv, const float* __restrict__ bv,
    f16* __restrict__ Qh, f16* __restrict__ Kh, f16* __restrict__ Vth)
{
    __shared__ f16 smem[128 * 64 + 64 * 64];
    f16* As = smem;
    f16* Bs = smem + 128 * 64;

    const int tid = threadIdx.x;
    const int w = tid >> 6, l = tid & 63;
    const int g = l >> 4, r = l & 15;

    const int m0 = blockIdx.x * 128;
    const int n0 = blockIdx.y * 64;
    const int mat = n0 >> 8;          // 0=Q 1=K 2=V
    const int ch0 = n0 & 255;

    const float* W    = (mat == 0) ? Wq : (mat == 1) ? Wk : Wv;
    const float* bias = (mat == 0) ? bq : (mat == 1) ? bk : bv;

    const int b  = m0 >> 11;
    const int l0 = m0 & 2047;

    f32x4 acc[2][4] = {};

    for (int k0 = 0; k0 < CC; k0 += 64) {
        #pragma unroll
        for (int m = 0; m < 4; ++m) {
            const int idx = m * 256 + tid;
            const int row = idx >> 3, c = idx & 7;
            const int lrow = l0 + row;
            const float* src = (lrow < LA)
                ? (audio + ((size_t)b * LA + lrow) * CC + k0 + c * 8)
                : (text  + ((size_t)b * LS + (lrow - LA)) * CC + k0 + c * 8);
            const float4 x0 = *(const float4*)src;
            const float4 x1 = *(const float4*)(src + 4);
            *(f16x8*)(As + row * 64 + ((c ^ (row & 7)) << 3)) = cvt8(x0, x1);
        }
        #pragma unroll
        for (int m = 0; m < 2; ++m) {
            const int idx = m * 256 + tid;
            const int row = idx >> 3, c = idx & 7;
            const float* src = W + (size_t)(ch0 + row) * CC + k0 + c * 8;
            const float4 x0 = *(const float4*)src;
            const float4 x1 = *(const float4*)(src + 4);
            *(f16x8*)(Bs + row * 64 + ((c ^ (row & 7)) << 3)) = cvt8(x0, x1);
        }
        __syncthreads();
        #pragma unroll
        for (int kc = 0; kc < 2; ++kc) {
            f16x8 af[2];
            #pragma unroll
            for (int i = 0; i < 2; ++i) {
                const int row = w * 32 + i * 16 + r;
                const int c = kc * 4 + g;
                af[i] = *(const f16x8*)(As + row * 64 + ((c ^ (row & 7)) << 3));
            }
            f16x8 bf[4];
            #pragma unroll
            for (int j = 0; j < 4; ++j) {
                const int row = j * 16 + r;
                const int c = kc * 4 + g;
                bf[j] = *(const f16x8*)(Bs + row * 64 + ((c ^ (row & 7)) << 3));
            }
            #pragma unroll
            for (int i = 0; i < 2; ++i)
                #pragma unroll
                for (int j = 0; j < 4; ++j)
                    acc[i][j] = __builtin_amdgcn_mfma_f32_16x16x32_f16(af[i], bf[j], acc[i][j], 0, 0, 0);
        }
        __syncthreads();
    }

    float bcol[4];
    #pragma unroll
    for (int j = 0; j < 4; ++j) bcol[j] = bias[ch0 + j * 16 + r];

    if (mat <= 1) {
        f16* Out = (mat == 0) ? Qh : Kh;
        const float osc = (mat == 0) ? QSCALE : 1.0f;
        #pragma unroll
        for (int i = 0; i < 2; ++i)
            #pragma unroll
            for (int e = 0; e < 4; ++e) {
                const int m = m0 + w * 32 + i * 16 + g * 4 + e;
                #pragma unroll
                for (int j = 0; j < 4; ++j)
                    Out[(size_t)m * CC + ch0 + j * 16 + r] =
                        (_Float16)((acc[i][j][e] + bcol[j]) * osc);
            }
    } else {
        // V: stage C^T in LDS (Ts[64 n][136 m-pad]), then coalesced vec8 store.
        f16* Ts = smem;
        #pragma unroll
        for (int i = 0; i < 2; ++i)
            #pragma unroll
            for (int e = 0; e < 4; ++e) {
                const int ml = w * 32 + i * 16 + g * 4 + e;
                #pragma unroll
                for (int j = 0; j < 4; ++j)
                    Ts[(j * 16 + r) * 136 + ml] = (_Float16)(acc[i][j][e] + bcol[j]);
            }
        __syncthreads();
        const int b2 = m0 >> 11, l0m = m0 & 2047;
        #pragma unroll
        for (int u = 0; u < 4; ++u) {
            const int idx = u * 256 + tid;
            const int nl = idx >> 4, mc = idx & 15;
            const f16x8 vv = *(const f16x8*)(Ts + nl * 136 + mc * 8);
            const int nglob = ch0 + nl;
            const int hh = nglob >> 6, dd = nglob & 63;
            *(f16x8*)(Vth + ((size_t)((b2 * NH + hh) * DKH + dd)) * LT + l0m + mc * 8) = vv;
        }
    }
}

// ---------------------------------------------------------------------------
// Kernel 2: flash attention, fp16 MFMA, inverted mask.
// R4 skeleton (512 thr, 2 tile-split groups x 4 waves, 16 q/wave) +
//  - K stored row-PERMUTED in LDS -> P stays in registers (Ps buffer gone)
//  - per-group double-buffered K/V -> ONE barrier per iteration
//  - exp2-domain softmax (QSCALE pre-folded into Q), exact defer-rescale
//  - group merge through union over the (dead) K/V buffers
// ---------------------------------------------------------------------------
__global__ __launch_bounds__(512) void attn_f16(
    const f16* __restrict__ Q, const f16* __restrict__ K,
    const f16* __restrict__ Vt,
    const int* __restrict__ slen, const int* __restrict__ tlen,
    f16* __restrict__ AO)
{
    __shared__ __align__(16) f16 KsA[2][2 * 4096];   // [group][buf][key' * 64 + d']
    __shared__ __align__(16) f16 VtsA[2][2 * 4096];  // [group][buf][d * 64 + key']

    const int tid = threadIdx.x;
    const int w = tid >> 6, l = tid & 63;
    const int gid = w >> 2, wg = w & 3;
    const int g = l >> 4, r = l & 15;
    const int tg = tid & 255;

    const int q0 = blockIdx.x * 64;
    const int h  = blockIdx.y;
    const int b  = blockIdx.z;

    const int ilen = slen[b];
    const int kcap = LA + tlen[b];
    const int nskip = ilen >> 6;
    int ntskip = 0;
    if (q0 >= LA) {
        const int skipmax = min(q0 - 63, kcap - 64);
        const int d = skipmax - LA;
        ntskip = (d < 0) ? 0 : ((d >> 6) + 1);
    }
    const int nAudio = NTA - nskip;                  // >= 1
    const int nProc  = nAudio + (NT - NTA) - ntskip; // >= 2
    const int nIter  = (nProc + 1) >> 1;

    const int qrow = q0 + 16 * wg + r;

    // Q fragment (QSCALE pre-folded by qkv_mfma)
    f16x8 qf[2];
    #pragma unroll
    for (int ch = 0; ch < 2; ++ch)
        qf[ch] = *(const f16x8*)(Q + ((size_t)(b * LT) + qrow) * CC + h * DKH + ch * 32 + g * 8);

    // staging (per group: 256 threads, rows srow0 / srow0+32, chunk scc)
    const int srow0 = tg >> 3, scc = tg & 7;
    const int srow1 = srow0 + 32;
    const int kp0 = PROW(srow0), kp1 = PROW(srow1);
    const int kdst0 = kp0 * 64 + ((scc ^ (kp0 & 7)) << 3);
    const int kdst1 = kp1 * 64 + ((scc ^ (kp1 & 7)) << 3);
    const int vdst0 = srow0 * 64 + ((scc ^ (srow0 & 7)) << 3);
    const int vdst1 = srow1 * 64 + ((scc ^ (srow1 & 7)) << 3);

    #define TILE_OF(p) ((p) < nAudio ? (nskip + (p)) : (NTA + ntskip + ((p) - nAudio)))

    {   // prologue: stage this group's first tile into buf 0
        const int k0 = TILE_OF(gid) * 64;
        *(f16x8*)(KsA[gid] + kdst0) =
            *(const f16x8*)(K + ((size_t)(b * LT) + k0 + srow0) * CC + h * DKH + scc * 8);
        *(f16x8*)(KsA[gid] + kdst1) =
            *(const f16x8*)(K + ((size_t)(b * LT) + k0 + srow1) * CC + h * DKH + scc * 8);
        *(f16x8*)(VtsA[gid] + vdst0) =
            *(const f16x8*)(Vt + ((size_t)((b * NH + h) * DKH) + srow0) * LT + k0 + scc * 8);
        *(f16x8*)(VtsA[gid] + vdst1) =
            *(const f16x8*)(Vt + ((size_t)((b * NH + h) * DKH) + srow1) * LT + k0 + scc * 8);
    }
    __syncthreads();

    float m_run = -1e30f, l_run = 0.0f;
    f32x4 o[4] = {};   // o[dsb][e]: O[q = 4g+e][d = 16*dsb + r]

    int cur = 0;
    for (int i = 0; i < nIter; ++i) {
        const int pcur = 2 * i + gid;
        const bool curV = pcur < nProc;
        const bool nxtV = (pcur + 2) < nProc;

        f16x8 kr0, kr1, vr0, vr1;
        if (nxtV) {     // issue next-tile loads early (hide HBM under compute)
            const int kn = TILE_OF(pcur + 2) * 64;
            kr0 = *(const f16x8*)(K + ((size_t)(b * LT) + kn + srow0) * CC + h * DKH + scc * 8);
            kr1 = *(const f16x8*)(K + ((size_t)(b * LT) + kn + srow1) * CC + h * DKH + scc * 8);
            vr0 = *(const f16x8*)(Vt + ((size_t)((b * NH + h) * DKH) + srow0) * LT + kn + scc * 8);
            vr1 = *(const f16x8*)(Vt + ((size_t)((b * NH + h) * DKH) + srow1) * LT + kn + scc * 8);
        }

        if (curV) {
            const int kt = TILE_OF(pcur);
            const int k0 = kt * 64;
            const f16* Kb = KsA[gid] + cur * 4096;
            const f16* Vb = VtsA[gid] + cur * 4096;

            // ---- S^T = K . Q^T  (K rows permuted: lane keys = kb + {s-pattern})
            f32x4 sacc[4] = {};
            #pragma unroll
            for (int s = 0; s < 4; ++s) {
                const int arow = 16 * s + r;
                #pragma unroll
                for (int ch = 0; ch < 2; ++ch) {
                    const f16x8 a = *(const f16x8*)(Kb + arow * 64 + (((ch * 4 + g) ^ (arow & 7)) << 3));
                    sacc[s] = __builtin_amdgcn_mfma_f32_16x16x32_f16(a, qf[ch], sacc[s], 0, 0, 0);
                }
            }

            // ---- mask (block-uniform mode); key of sacc[s][e] = kb + 32*(s>>1)+4*(s&1)+e
            const int mode = (kt < NTA) ? ((k0 >= ilen) ? 0 : 1)
                                        : ((q0 < LA) ? 0 : 2);
            const int kb = k0 + 8 * g;
            float sv[16];
            if (mode == 0) {
                #pragma unroll
                for (int s = 0; s < 4; ++s)
                    #pragma unroll
                    for (int e = 0; e < 4; ++e) sv[s * 4 + e] = sacc[s][e];
            } else if (mode == 1) {
                #pragma unroll
                for (int s = 0; s < 4; ++s)
                    #pragma unroll
                    for (int e = 0; e < 4; ++e) {
                        const int kk = kb + 32 * (s >> 1) + 4 * (s & 1) + e;
                        sv[s * 4 + e] = (kk >= ilen) ? sacc[s][e] : -INFINITY;
                    }
            } else {
                #pragma unroll
                for (int s = 0; s < 4; ++s)
                    #pragma unroll
                    for (int e = 0; e < 4; ++e) {
                        const int kk = kb + 32 * (s >> 1) + 4 * (s & 1) + e;
                        sv[s * 4 + e] = (kk > qrow || kk >= kcap) ? sacc[s][e] : -INFINITY;
                    }
            }

            // ---- online softmax, exp2 domain, finite sentinel
            float mloc = -1e30f;
            #pragma unroll
            for (int u = 0; u < 16; ++u) mloc = fmaxf(mloc, sv[u]);
            mloc = fmaxf(mloc, __shfl_xor(mloc, 16));
            mloc = fmaxf(mloc, __shfl_xor(mloc, 32));
            const float m_new = fmaxf(m_run, mloc);

            float ssum = 0.0f;
            f16x4 ph[4];
            #pragma unroll
            for (int s = 0; s < 4; ++s)
                #pragma unroll
                for (int e = 0; e < 4; ++e) {
                    const float p = exp2f(sv[s * 4 + e] - m_new);   // exp2(-inf)=0
                    ph[s][e] = (_Float16)p;
                    ssum += p;
                }
            ssum += __shfl_xor(ssum, 16);
            ssum += __shfl_xor(ssum, 32);

            if (__all(m_new == m_run)) {           // exact defer (sc==1)
                l_run += ssum;
            } else {
                const float sc = exp2f(m_run - m_new);
                l_run = l_run * sc + ssum;
                m_run = m_new;
                #pragma unroll
                for (int e = 0; e < 4; ++e) {
                    const float scr = __shfl(sc, 4 * g + e);
                    #pragma unroll
                    for (int dsb = 0; dsb < 4; ++dsb) o[dsb][e] *= scr;
                }
            }

            // ---- O += P . V   (A-frag = own registers, thanks to PROW)
            #pragma unroll
            for (int ch = 0; ch < 2; ++ch) {
                f16x8 a;
                #pragma unroll
                for (int e = 0; e < 4; ++e) { a[e] = ph[2 * ch][e]; a[4 + e] = ph[2 * ch + 1][e]; }
                #pragma unroll
                for (int dsb = 0; dsb < 4; ++dsb) {
                    const int vrow = 16 * dsb + r;
                    const f16x8 bf = *(const f16x8*)(Vb + vrow * 64 + (((ch * 4 + g) ^ (vrow & 7)) << 3));
                    o[dsb] = __builtin_amdgcn_mfma_f32_16x16x32_f16(a, bf, o[dsb], 0, 0, 0);
                }
            }
        }

        if (nxtV) {     // write staged regs into the other buffer
            f16* Kn = KsA[gid] + (cur ^ 1) * 4096;
            f16* Vn = VtsA[gid] + (cur ^ 1) * 4096;
            *(f16x8*)(Kn + kdst0) = kr0;
            *(f16x8*)(Kn + kdst1) = kr1;
            *(f16x8*)(Vn + vdst0) = vr0;
            *(f16x8*)(Vn + vdst1) = vr1;
        }
        __syncthreads();          // next buf ready AND cur-buf reads complete
        cur ^= 1;
    }

    // ---- merge group partials through union over dead K/V buffers
    float* OcF = (float*)&KsA[0][0];    // [wg*4+dsb][lane*4+e] : 16 KB
    float* ML1 = (float*)&VtsA[0][0];   // [qloc][2] : 512 B
    if (gid == 1) {
        #pragma unroll
        for (int dsb = 0; dsb < 4; ++dsb)
            *(f32x4*)(OcF + ((wg * 4 + dsb) << 8) + (l << 2)) = o[dsb];
        if (g == 0) {
            ML1[(16 * wg + r) * 2 + 0] = m_run;
            ML1[(16 * wg + r) * 2 + 1] = l_run;
        }
    }
    __syncthreads();

    if (gid == 0) {
        #pragma unroll
        for (int e = 0; e < 4; ++e) {
            const int qloc = 16 * wg + 4 * g + e;
            const float m0v = __shfl(m_run, 4 * g + e);
            const float l0v = __shfl(l_run, 4 * g + e);
            const float m1v = ML1[qloc * 2 + 0];
            const float l1v = ML1[qloc * 2 + 1];
            const float mt = fmaxf(m0v, m1v);
            const float c0 = exp2f(m0v - mt);
            const float c1 = exp2f(m1v - mt);
            const float inv = 1.0f / (l0v * c0 + l1v * c1);
            #pragma unroll
            for (int dsb = 0; dsb < 4; ++dsb) {
                const float v = (o[dsb][e] * c0
                               + OcF[((wg * 4 + dsb) << 8) + (l << 2) + e] * c1) * inv;
                AO[((size_t)(b * LT) + q0 + qloc) * CC + h * DKH + 16 * dsb + r] = (_Float16)v;
            }
        }
    }
    #undef TILE_OF
}

// ---------------------------------------------------------------------------
// Kernel 3: output projection, fp16 MFMA (X already f16), fp32 out.
// ---------------------------------------------------------------------------
__global__ __launch_bounds__(256) void out_mfma(
    const f16* __restrict__ X, const float* __restrict__ Wo,
    const float* __restrict__ bo, float* __restrict__ Out)
{
    __shared__ f16 As[128 * 64];
    __shared__ f16 Bs[64 * 64];

    const int tid = threadIdx.x;
    const int w = tid >> 6, l = tid & 63;
    const int g = l >> 4, r = l & 15;

    const int m0 = blockIdx.x * 128;
    const int n0 = blockIdx.y * 64;

    f32x4 acc[2][4] = {};

    for (int k0 = 0; k0 < CC; k0 += 64) {
        #pragma unroll
        for (int m = 0; m < 4; ++m) {
            const int idx = m * 256 + tid;
            const int row = idx >> 3, c = idx & 7;
            *(f16x8*)(As + row * 64 + ((c ^ (row & 7)) << 3)) =
                *(const f16x8*)(X + (size_t)(m0 + row) * CC + k0 + c * 8);
        }
        #pragma unroll
        for (int m = 0; m < 2; ++m) {
            const int idx = m * 256 + tid;
            const int row = idx >> 3, c = idx & 7;
            const float* src = Wo + (size_t)(n0 + row) * CC + k0 + c * 8;
            const float4 x0 = *(const float4*)src;
            const float4 x1 = *(const float4*)(src + 4);
            *(f16x8*)(Bs + row * 64 + ((c ^ (row & 7)) << 3)) = cvt8(x0, x1);
        }
        __syncthreads();
        #pragma unroll
        for (int kc = 0; kc < 2; ++kc) {
            f16x8 af[2];
            #pragma unroll
            for (int i = 0; i < 2; ++i) {
                const int row = w * 32 + i * 16 + r;
                const int c = kc * 4 + g;
                af[i] = *(const f16x8*)(As + row * 64 + ((c ^ (row & 7)) << 3));
            }
            f16x8 bf[4];
            #pragma unroll
            for (int j = 0; j < 4; ++j) {
                const int row = j * 16 + r;
                const int c = kc * 4 + g;
                bf[j] = *(const f16x8*)(Bs + row * 64 + ((c ^ (row & 7)) << 3));
            }
            #pragma unroll
            for (int i = 0; i < 2; ++i)
                #pragma unroll
                for (int j = 0; j < 4; ++j)
                    acc[i][j] = __builtin_amdgcn_mfma_f32_16x16x32_f16(af[i], bf[j], acc[i][j], 0, 0, 0);
        }
        __syncthreads();
    }

    float bcol[4];
    #pragma unroll
    for (int j = 0; j < 4; ++j) bcol[j] = bo[n0 + j * 16 + r];

    #pragma unroll
    for (int i = 0; i < 2; ++i)
        #pragma unroll
        for (int e = 0; e < 4; ++e) {
            const int m = m0 + w * 32 + i * 16 + g * 4 + e;
            #pragma unroll
            for (int j = 0; j < 4; ++j)
                Out[(size_t)m * CC + n0 + j * 16 + r] = acc[i][j][e] + bcol[j];
        }
}

// ---------------------------------------------------------------------------
extern "C" void kernel_launch(void* const* d_in, const int* in_sizes, int n_in,
                              void* d_out, int out_size, void* d_ws, size_t ws_size,
                              hipStream_t stream)
{
    const float* audio = (const float*)d_in[0];
    const float* text  = (const float*)d_in[1];
    const int*   slen  = (const int*)d_in[2];
    const int*   tlen  = (const int*)d_in[3];
    const float* Wq = (const float*)d_in[4];
    const float* bq = (const float*)d_in[5];
    const float* Wk = (const float*)d_in[6];
    const float* bk = (const float*)d_in[7];
    const float* Wv = (const float*)d_in[8];
    const float* bv = (const float*)d_in[9];
    const float* Wo = (const float*)d_in[10];
    const float* bo = (const float*)d_in[11];
    float* out = (float*)d_out;

    f16* Qh  = (f16*)d_ws;
    f16* Kh  = Qh + SZ;
    f16* Vth = Kh + SZ;
    f16* AOh = Vth + SZ;

    qkv_mfma<<<dim3(64, 12), 256, 0, stream>>>(audio, text, Wq, bq, Wk, bk, Wv, bv,
                                               Qh, Kh, Vth);
    attn_f16<<<dim3(LT / 64, NH, NB), 512, 0, stream>>>(Qh, Kh, Vth, slen, tlen, AOh);
    out_mfma<<<dim3(64, 4), 256, 0, stream>>>(AOh, Wo, bo, out);
}